// Round 2
// baseline (279.401 us; speedup 1.0000x reference)
//
#include <hip/hip_runtime.h>

// ---------------------------------------------------------------------------
// TransVLAD fused pipeline for MI355X (gfx950)
// Shapes: N=32, C=512, H=W=32 (P=1024), E=1024, G=8, D=128, K=64
// out: [N, K*D] fp32 (262144)
//
// R8: K4 was barrier-drain bound (MfmaUtil 16%, VALUBusy 21%, HBM 21%,
// occupancy grid-capped at 2 blocks/CU): 16 full vmcnt(0) drains per cc.
// T3+T4 port: S-phase B-tile double-buffered, raw s_barrier with COUNTED
// s_waitcnt vmcnt(12) (next tile stays in flight across the barrier).
// As2 stage dropped: A=Vb[g] is cc/ks-invariant, read as register fragments
// straight from L2, double-buffered 1 ks ahead in the same vmcnt pipeline.
// xg stage moved to ks=6 (no intermediate counted wait forces its drain;
// completes under MFMA(6..7)+softmax). xglds compacted to swizzled
// [128][128]; wlds aliases dead Bs buffers. LDS 76.8 -> 64 KB.
// ---------------------------------------------------------------------------

#define N_  32
#define C_  512
#define P_  1024
#define E_  1024
#define G_  8
#define D_  128
#define K_  64

typedef __attribute__((ext_vector_type(8))) short bf16x8;
typedef __attribute__((ext_vector_type(4))) float f32x4;

__device__ __forceinline__ unsigned short f2b(float f) {
    union { float f; unsigned u; } v; v.f = f;
    unsigned r = (v.u + 0x7FFFu + ((v.u >> 16) & 1u)) >> 16;
    return (unsigned short)r;
}
__device__ __forceinline__ float b2f(unsigned short h) {
    union { unsigned u; float f; } v; v.u = ((unsigned)h) << 16;
    return v.f;
}

// async global->LDS 16B copy: LDS dest must be wave-uniform base + lane*16
__device__ __forceinline__ void gl_lds16(const void* g, void* l) {
    __builtin_amdgcn_global_load_lds(
        (const __attribute__((address_space(1))) void*)g,
        (__attribute__((address_space(3))) void*)l, 16, 0, 0);
}

#define SB  __builtin_amdgcn_sched_barrier(0)
#define BAR __builtin_amdgcn_s_barrier()

// ---------------------------------------------------------------------------
// K0: convert W1 -> bf16 AND build V[g][k][c] = sum_d Wc[k][d]*W1[g*128+d][c]
__global__ __launch_bounds__(256) void k0_prep(const float* __restrict__ W1,
                                               const float* __restrict__ Wc,
                                               unsigned short* __restrict__ W1b,
                                               unsigned short* __restrict__ Vb) {
    int bid = blockIdx.x;
    int t = threadIdx.x;
    int i0 = bid * 512 + t;
    W1b[i0]       = f2b(W1[i0]);
    W1b[i0 + 256] = f2b(W1[i0 + 256]);
    int ch = bid & 1, k = (bid >> 1) & 63, g = bid >> 7;
    int c = ch * 256 + t;
    float acc = 0.f;
    #pragma unroll 8
    for (int d = 0; d < 128; ++d)
        acc += Wc[k * 128 + d] * W1[(g * 128 + d) * C_ + c];
    Vb[(g * 64 + k) * C_ + c] = f2b(acc);
}

// ---------------------------------------------------------------------------
// K1: per-pixel L2 norm over C, write x_hat transposed: xhat_t [N][P][C] bf16
__global__ __launch_bounds__(256) void k1_norm_transpose(const float* __restrict__ x,
                                                         unsigned short* __restrict__ xhat_t) {
    __shared__ short xc[128 * 256];   // [i][t]: c = (t>>6)*128+i, p = p0+(t&63)
    __shared__ float red[256];
    __shared__ float rn[64];
    int n = blockIdx.y;
    int p0 = blockIdx.x * 64;
    int t = threadIdx.x;
    int ps = t & 63, cs = t >> 6;

    float ss = 0.f;
    for (int i = 0; i < 128; ++i) {
        float v = x[((size_t)(n * C_ + cs * 128 + i)) * P_ + p0 + ps];
        ss += v * v;
        xc[i * 256 + t] = (short)f2b(v);     // lanes consecutive -> conflict-free
    }
    red[t] = ss;
    __syncthreads();
    if (t < 64) {
        float s = red[t] + red[64 + t] + red[128 + t] + red[192 + t];
        rn[t] = 1.0f / fmaxf(sqrtf(s), 1e-12f);
    }
    __syncthreads();

    float r = rn[ps];
    size_t base = ((size_t)(n * P_ + p0 + ps)) * C_ + cs * 128;
    #pragma unroll
    for (int jj = 0; jj < 16; ++jj) {
        bf16x8 o;
        #pragma unroll
        for (int j = 0; j < 8; ++j)
            o[j] = (short)f2b(b2f((unsigned short)xc[(jj * 8 + j) * 256 + t]) * r);
        *(bf16x8*)&xhat_t[base + jj * 8] = o;
    }
}

// ---------------------------------------------------------------------------
// K2: xe[n][e][p] = sum_c W1b[e][c] * xhat_t[n][p][c]   (bf16 MFMA GEMM, NT)
// grid (64, 32). BK=64, XOR-swizzled LDS columns (chunk ^= row&7).
__global__ __launch_bounds__(256) void k2_gemm_xe(const unsigned short* __restrict__ W1b,
                                                  const unsigned short* __restrict__ xhat_t,
                                                  unsigned short* __restrict__ xe) {
    __shared__ __align__(16) short As[128 * 64];
    __shared__ __align__(16) short Bs[128 * 64];
    int n = blockIdx.y;
    int e0 = (blockIdx.x >> 3) * 128;
    int p0 = (blockIdx.x & 7) * 128;
    int t = threadIdx.x;
    int w = t >> 6, l = t & 63, q = l >> 4, l15 = l & 15;
    int wr = w >> 1, wc = w & 1;

    f32x4 acc[4][4];
    #pragma unroll
    for (int mi = 0; mi < 4; ++mi)
        #pragma unroll
        for (int ni = 0; ni < 4; ++ni)
            acc[mi][ni] = (f32x4){0.f, 0.f, 0.f, 0.f};

    for (int ks = 0; ks < 8; ++ks) {
        int k0 = ks * 64;
        #pragma unroll
        for (int i = 0; i < 4; ++i) {
            int ch = i * 256 + t;
            int row = ch >> 3, c8 = ch & 7;
            gl_lds16(&W1b[(e0 + row) * C_ + k0 + ((c8 ^ (row & 7)) * 8)], &As[ch * 8]);
        }
        #pragma unroll
        for (int i = 0; i < 4; ++i) {
            int ch = i * 256 + t;
            int row = ch >> 3, c8 = ch & 7;
            gl_lds16(&xhat_t[((size_t)(n * P_ + p0 + row)) * C_ + k0 + ((c8 ^ (row & 7)) * 8)], &Bs[ch * 8]);
        }
        __syncthreads();

        #pragma unroll
        for (int kk = 0; kk < 2; ++kk) {
            bf16x8 af[4], bf[4];
            #pragma unroll
            for (int mi = 0; mi < 4; ++mi)
                af[mi] = *(const bf16x8*)&As[(wr * 64 + mi * 16 + l15) * 64 + (((kk * 4 + q) ^ (l15 & 7)) * 8)];
            #pragma unroll
            for (int ni = 0; ni < 4; ++ni)
                bf[ni] = *(const bf16x8*)&Bs[(wc * 64 + ni * 16 + l15) * 64 + (((kk * 4 + q) ^ (l15 & 7)) * 8)];
            #pragma unroll
            for (int mi = 0; mi < 4; ++mi)
                #pragma unroll
                for (int ni = 0; ni < 4; ++ni)
                    acc[mi][ni] = __builtin_amdgcn_mfma_f32_16x16x32_bf16(af[mi], bf[ni], acc[mi][ni], 0, 0, 0);
        }
        __syncthreads();
    }

    #pragma unroll
    for (int mi = 0; mi < 4; ++mi) {
        #pragma unroll
        for (int ni = 0; ni < 4; ++ni) {
            #pragma unroll
            for (int r = 0; r < 4; ++r) {
                int e = e0 + wr * 64 + mi * 16 + q * 4 + r;
                int p = p0 + wc * 64 + ni * 16 + l15;
                xe[((size_t)(n * E_ + e)) * P_ + p] = f2b(acc[mi][ni][r]);
            }
        }
    }
}

// ---------------------------------------------------------------------------
// K3a: att partials over 64-wide e-chunks, 4 pixels/thread (ushort4/float4).
__global__ __launch_bounds__(256) void k3a_att_part(const unsigned short* __restrict__ xe,
                                                    const float* __restrict__ W2,
                                                    float* __restrict__ att_part) {
    int n = blockIdx.y;
    int ec = blockIdx.x;
    int t = threadIdx.x;
    int e0 = ec * 64;
    f32x4 acc[8];
    #pragma unroll
    for (int g = 0; g < 8; ++g) acc[g] = (f32x4){0.f, 0.f, 0.f, 0.f};
    #pragma unroll 4
    for (int i = 0; i < 64; ++i) {
        int e = e0 + i;
        ushort4 v4 = *(const ushort4*)&xe[((size_t)(n * E_ + e)) * P_ + t * 4];
        f32x4 vf = {b2f(v4.x), b2f(v4.y), b2f(v4.z), b2f(v4.w)};
        #pragma unroll
        for (int g = 0; g < 8; ++g)
            acc[g] += vf * W2[g * E_ + e];
    }
    #pragma unroll
    for (int g = 0; g < 8; ++g)
        *(f32x4*)&att_part[(((size_t)(n * 16 + ec)) * 8 + g) * P_ + t * 4] = acc[g];
}

// K3b: att_s[n][g][p] = sigmoid( sum_ec att_part[n][ec][g][p] )
__global__ __launch_bounds__(256) void k3b_att_reduce(const float* __restrict__ att_part,
                                                      float* __restrict__ att_s) {
    int idx = blockIdx.x * 256 + threadIdx.x;
    int p = idx & 1023;
    int g = (idx >> 10) & 7;
    int n = idx >> 13;
    float s = 0.f;
    #pragma unroll
    for (int ec = 0; ec < 16; ++ec)
        s += att_part[(((size_t)(n * 16 + ec)) * 8 + g) * P_ + p];
    att_s[idx] = 1.0f / (1.0f + __expf(-s));
}

// ---------------------------------------------------------------------------
// K4 helpers
__device__ __forceinline__ void load_af(bf16x8* dst, const unsigned short* __restrict__ Vb,
                                        int g, int ks, int l15, int q) {
    #pragma unroll
    for (int mi = 0; mi < 4; ++mi)
        #pragma unroll
        for (int kk = 0; kk < 2; ++kk)
            dst[mi * 2 + kk] = *(const bf16x8*)&Vb[(size_t)((g * 64 + mi * 16 + l15) * C_)
                                                  + ks * 64 + kk * 32 + q * 8];
}

__device__ __forceinline__ void stage_b(short* buf, const unsigned short* __restrict__ xhat_t,
                                        int n, int p0c, int k0, int t) {
    #pragma unroll
    for (int i = 0; i < 4; ++i) {
        int ch = i * 256 + t;
        int row = ch >> 3, c8 = ch & 7;
        gl_lds16(&xhat_t[((size_t)(n * P_ + p0c + row)) * C_ + k0 + ((c8 ^ (row & 7)) * 8)],
                 &buf[ch * 8]);
    }
}

__device__ __forceinline__ void stage_xg(short* xglds, const unsigned short* __restrict__ xe,
                                         int n, int g, int p0c, int t) {
    #pragma unroll
    for (int i = 0; i < 8; ++i) {
        int ch = i * 256 + t;
        int row = ch >> 4, c16 = ch & 15;
        gl_lds16(&xe[((size_t)(n * E_ + g * 128 + row)) * P_ + p0c + ((c16 ^ (row & 7)) * 8)],
                 &xglds[ch * 8]);
    }
}

__device__ __forceinline__ void mfma_s(f32x4 acc[4][2], const short* buf, const bf16x8* af,
                                       int w, int q, int l15) {
    #pragma unroll
    for (int kk = 0; kk < 2; ++kk) {
        bf16x8 b[2];
        #pragma unroll
        for (int ni = 0; ni < 2; ++ni)
            b[ni] = *(const bf16x8*)&buf[(w * 32 + ni * 16 + l15) * 64
                                         + (((kk * 4 + q) ^ (l15 & 7)) * 8)];
        #pragma unroll
        for (int mi = 0; mi < 4; ++mi)
            #pragma unroll
            for (int ni = 0; ni < 2; ++ni)
                acc[mi][ni] = __builtin_amdgcn_mfma_f32_16x16x32_bf16(
                    af[mi * 2 + kk], b[ni], acc[mi][ni], 0, 0, 0);
    }
}

// ---------------------------------------------------------------------------
// K4: fused assignment -> softmax -> gate -> aggregation per (n, g, ph)
// grid (16, 32). Counted-vmcnt double-buffered S-phase; A from L2 registers.
__global__ __launch_bounds__(256) void k4_assign_agg(const unsigned short* __restrict__ Vb,
                                                     const unsigned short* __restrict__ xhat_t,
                                                     const unsigned short* __restrict__ xe,
                                                     const float* __restrict__ att_s,
                                                     float* __restrict__ agg_part,
                                                     float* __restrict__ wsum_part) {
    __shared__ __align__(16) char smem[65536];
    short* Bs0   = (short*)smem;                 // 16 KB buf0 (S-phase B tile)
    short* Bs1   = (short*)(smem + 16384);       // 16 KB buf1
    short* xglds = (short*)(smem + 32768);       // [128][128] 32 KB, XOR-swizzled
    short* wlds  = (short*)smem;                 // [64][136] 17.4 KB alias (Bs dead)

    // XCD-aware remap (bijective: 512 blocks, 512 % 8 == 0)
    int b = blockIdx.y * 16 + blockIdx.x;
    int work = (b & 7) * 64 + (b >> 3);
    int n = work >> 4, g = work & 7, ph = (work >> 3) & 1;

    int t = threadIdx.x;
    int w = t >> 6, l = t & 63, q = l >> 4, l15 = l & 15;

    f32x4 acc_a[4][2];
    #pragma unroll
    for (int mi = 0; mi < 4; ++mi)
        #pragma unroll
        for (int ni = 0; ni < 2; ++ni)
            acc_a[mi][ni] = (f32x4){0.f, 0.f, 0.f, 0.f};
    float wsp[16];
    #pragma unroll
    for (int j = 0; j < 16; ++j) wsp[j] = 0.f;

    #pragma unroll 1
    for (int cc = 0; cc < 4; ++cc) {
        int p0c = ph * 512 + cc * 128;

        f32x4 acc_s[4][2];
        #pragma unroll
        for (int mi = 0; mi < 4; ++mi)
            #pragma unroll
            for (int ni = 0; ni < 2; ++ni)
                acc_s[mi][ni] = (f32x4){0.f, 0.f, 0.f, 0.f};

        bf16x8 afA[8], afB[8];

        // ---- prologue (14 VMEM ops): B0 DMA(4), afA(8), att(2) ----
        stage_b(Bs0, xhat_t, n, p0c, 0, t); SB;
        load_af(afA, Vb, g, 0, l15, q); SB;
        float av0 = att_s[(size_t)(n * G_ + g) * P_ + p0c + w * 32 + l15];
        float av1 = att_s[(size_t)(n * G_ + g) * P_ + p0c + w * 32 + 16 + l15];
        SB;

        // ---- ks=0 : prefetch ks=1, wait prologue, compute Bs0/afA ----
        load_af(afB, Vb, g, 1, l15, q); SB;
        stage_b(Bs1, xhat_t, n, p0c, 64, t); SB;
        asm volatile("s_waitcnt vmcnt(12)" ::: "memory"); SB; BAR; SB;
        mfma_s(acc_s, Bs0, afA, w, q, l15); SB; BAR; SB;
        // ---- ks=1 ----
        load_af(afA, Vb, g, 2, l15, q); SB;
        stage_b(Bs0, xhat_t, n, p0c, 128, t); SB;
        asm volatile("s_waitcnt vmcnt(12)" ::: "memory"); SB; BAR; SB;
        mfma_s(acc_s, Bs1, afB, w, q, l15); SB; BAR; SB;
        // ---- ks=2 ----
        load_af(afB, Vb, g, 3, l15, q); SB;
        stage_b(Bs1, xhat_t, n, p0c, 192, t); SB;
        asm volatile("s_waitcnt vmcnt(12)" ::: "memory"); SB; BAR; SB;
        mfma_s(acc_s, Bs0, afA, w, q, l15); SB; BAR; SB;
        // ---- ks=3 ----
        load_af(afA, Vb, g, 4, l15, q); SB;
        stage_b(Bs0, xhat_t, n, p0c, 256, t); SB;
        asm volatile("s_waitcnt vmcnt(12)" ::: "memory"); SB; BAR; SB;
        mfma_s(acc_s, Bs1, afB, w, q, l15); SB; BAR; SB;
        // ---- ks=4 ----
        load_af(afB, Vb, g, 5, l15, q); SB;
        stage_b(Bs1, xhat_t, n, p0c, 320, t); SB;
        asm volatile("s_waitcnt vmcnt(12)" ::: "memory"); SB; BAR; SB;
        mfma_s(acc_s, Bs0, afA, w, q, l15); SB; BAR; SB;
        // ---- ks=5 ----
        load_af(afA, Vb, g, 6, l15, q); SB;
        stage_b(Bs0, xhat_t, n, p0c, 384, t); SB;
        asm volatile("s_waitcnt vmcnt(12)" ::: "memory"); SB; BAR; SB;
        mfma_s(acc_s, Bs1, afB, w, q, l15); SB; BAR; SB;
        // ---- ks=6 : also issue xg DMA (8) AFTER af7/B7 so only the final
        //      __syncthreads drains it (covered by MFMA(6..7)+softmax) ----
        load_af(afB, Vb, g, 7, l15, q); SB;
        stage_b(Bs1, xhat_t, n, p0c, 448, t); SB;
        stage_xg(xglds, xe, n, g, p0c, t); SB;
        asm volatile("s_waitcnt vmcnt(20)" ::: "memory"); SB; BAR; SB;
        mfma_s(acc_s, Bs0, afA, w, q, l15); SB; BAR; SB;
        // ---- ks=7 : allow xg (8) outstanding ----
        asm volatile("s_waitcnt vmcnt(8)" ::: "memory"); SB; BAR; SB;
        mfma_s(acc_s, Bs1, afB, w, q, l15); SB; BAR; SB;

        // ---- softmax over k + gate (writes wlds, aliased over dead Bs) ----
        #pragma unroll
        for (int ni = 0; ni < 2; ++ni) {
            float m = -1e30f;
            #pragma unroll
            for (int mi = 0; mi < 4; ++mi)
                #pragma unroll
                for (int r = 0; r < 4; ++r)
                    m = fmaxf(m, acc_s[mi][ni][r]);
            m = fmaxf(m, __shfl_xor(m, 16));
            m = fmaxf(m, __shfl_xor(m, 32));
            float s = 0.f;
            #pragma unroll
            for (int mi = 0; mi < 4; ++mi)
                #pragma unroll
                for (int r = 0; r < 4; ++r) {
                    float e = __expf(acc_s[mi][ni][r] - m);
                    acc_s[mi][ni][r] = e;
                    s += e;
                }
            s += __shfl_xor(s, 16);
            s += __shfl_xor(s, 32);

            float av = ni ? av1 : av0;   // pre-sigmoided
            float scale = av / s;

            #pragma unroll
            for (int mi = 0; mi < 4; ++mi)
                #pragma unroll
                for (int r = 0; r < 4; ++r) {
                    float wv = acc_s[mi][ni][r] * scale;
                    wsp[mi * 4 + r] += wv;
                    wlds[(mi * 16 + q * 4 + r) * 136 + (w * 32 + ni * 16 + l15)] = (short)f2b(wv);
                }
        }
        __syncthreads();   // drains xg DMA (vmcnt) + wlds writes (lgkmcnt)

        // ---- agg MFMA: A = w [64k x 128p], B = xg [128d x 128p] (NT) ----
        #pragma unroll
        for (int pk = 0; pk < 4; ++pk) {
            bf16x8 a2[4], b2[2];
            #pragma unroll
            for (int mi = 0; mi < 4; ++mi)
                a2[mi] = *(const bf16x8*)&wlds[(mi * 16 + l15) * 136 + pk * 32 + q * 8];
            #pragma unroll
            for (int ni = 0; ni < 2; ++ni)
                b2[ni] = *(const bf16x8*)&xglds[(w * 32 + ni * 16 + l15) * 128
                                                + (((pk * 4 + q) ^ (l15 & 7)) * 8)];
            #pragma unroll
            for (int mi = 0; mi < 4; ++mi)
                #pragma unroll
                for (int ni = 0; ni < 2; ++ni)
                    acc_a[mi][ni] = __builtin_amdgcn_mfma_f32_16x16x32_bf16(a2[mi], b2[ni], acc_a[mi][ni], 0, 0, 0);
        }
        __syncthreads();   // xglds/wlds reads done before next cc re-stages
    }

    // ---- epilogue: disjoint partials, no atomics ----
    size_t base = (((size_t)(n * G_ + g)) * 2 + ph) * 64;
    #pragma unroll
    for (int mi = 0; mi < 4; ++mi)
        #pragma unroll
        for (int ni = 0; ni < 2; ++ni)
            #pragma unroll
            for (int r = 0; r < 4; ++r) {
                int k = mi * 16 + q * 4 + r;
                int d = w * 32 + ni * 16 + l15;
                agg_part[(base + k) * 128 + d] = acc_a[mi][ni][r];
            }

    #pragma unroll
    for (int j = 0; j < 16; ++j) {
        float v = wsp[j];
        v += __shfl_xor(v, 1);
        v += __shfl_xor(v, 2);
        v += __shfl_xor(v, 4);
        v += __shfl_xor(v, 8);
        if (l15 == 0) {
            int k = (j >> 2) * 16 + q * 4 + (j & 3);
            wsum_part[((((size_t)(n * G_ + g)) * 2 + ph) * 4 + w) * 64 + k] = v;
        }
    }
}

// ---------------------------------------------------------------------------
// K5: vlad[n][k][d] = sum_{g,ph} agg_part - (sum) * centroids
__global__ __launch_bounds__(256) void k5_final(const float* __restrict__ agg_part,
                                                const float* __restrict__ wsum_part,
                                                const float* __restrict__ centroids,
                                                float* __restrict__ out) {
    int idx = blockIdx.x * 256 + threadIdx.x;
    int d = idx & 127;
    int k = (idx >> 7) & 63;
    int n = idx >> 13;
    float ws = 0.f;
    #pragma unroll
    for (int g = 0; g < 8; ++g)
        #pragma unroll
        for (int ph = 0; ph < 2; ++ph)
            #pragma unroll
            for (int w2 = 0; w2 < 4; ++w2)
                ws += wsum_part[((((size_t)(n * G_ + g)) * 2 + ph) * 4 + w2) * 64 + k];
    float agg = 0.f;
    #pragma unroll
    for (int g = 0; g < 8; ++g)
        #pragma unroll
        for (int ph = 0; ph < 2; ++ph)
            agg += agg_part[(((((size_t)(n * G_ + g)) * 2 + ph) * 64) + k) * 128 + d];
    out[idx] = agg - ws * centroids[k * 128 + d];
}

// ---------------------------------------------------------------------------
extern "C" void kernel_launch(void* const* d_in, const int* in_sizes, int n_in,
                              void* d_out, int out_size, void* d_ws, size_t ws_size,
                              hipStream_t stream) {
    const float* x         = (const float*)d_in[0];
    const float* W1        = (const float*)d_in[1];
    const float* W2        = (const float*)d_in[2];
    const float* Wc        = (const float*)d_in[3];
    const float* centroids = (const float*)d_in[4];
    float* out = (float*)d_out;

    // Workspace layout (total 120,324,096 B == proven footprint):
    //   W1b      [E*C]        bf16   1,048,576 B @ 0
    //   Vb       [G*K*C]      bf16     524,288 B @ 1,048,576
    //   xhat_t   [N*P*C]      bf16  33,554,432 B @ 1,572,864
    //   xe       [N*E*P]      bf16  67,108,864 B @ 35,127,296
    //   att_s    [N*G*P]      f32    1,048,576 B @ 102,236,160
    //   att_part [N*16*G*P]   f32   16,777,216 B @ 103,284,736 (dead after k3b;
    //   agg_part [N*G*2*K*D]  f32   16,777,216 B @ 103,284,736  aliases att_part)
    //   wsum_part[N*G*2*4*K]  f32      262,144 B @ 120,061,952
    char* ws = (char*)d_ws;
    unsigned short* W1b      = (unsigned short*)(ws + 0);
    unsigned short* Vb       = (unsigned short*)(ws + 1048576);
    unsigned short* xhat_t   = (unsigned short*)(ws + 1572864);
    unsigned short* xe       = (unsigned short*)(ws + 35127296);
    float*          att_s    = (float*)(ws + 102236160);
    float*          att_part = (float*)(ws + 103284736);
    float*          agg_part = (float*)(ws + 103284736);   // alias: att_part dead before K4
    float*          wsum_part= (float*)(ws + 120061952);

    hipLaunchKernelGGL(k0_prep,        dim3(1024), dim3(256), 0, stream, W1, Wc, W1b, Vb);
    hipLaunchKernelGGL(k1_norm_transpose, dim3(16, 32), dim3(256), 0, stream, x, xhat_t);
    hipLaunchKernelGGL(k2_gemm_xe,     dim3(64, 32), dim3(256), 0, stream, W1b, xhat_t, xe);
    hipLaunchKernelGGL(k3a_att_part,   dim3(16, 32), dim3(256), 0, stream, xe, W2, att_part);
    hipLaunchKernelGGL(k3b_att_reduce, dim3(1024), dim3(256), 0, stream, att_part, att_s);
    hipLaunchKernelGGL(k4_assign_agg,  dim3(16, 32), dim3(256), 0, stream, Vb, xhat_t, xe,
                       att_s, agg_part, wsum_part);
    hipLaunchKernelGGL(k5_final,       dim3(1024), dim3(256), 0, stream,
                       agg_part, wsum_part, centroids, out);
}

// Round 3
// 233.314 us; speedup vs baseline: 1.1975x; 1.1975x over previous
//
#include <hip/hip_runtime.h>

// ---------------------------------------------------------------------------
// TransVLAD fused pipeline for MI355X (gfx950)
// Shapes: N=32, C=512, H=W=32 (P=1024), E=1024, G=8, D=128, K=64
// out: [N, K*D] fp32 (262144)
//
// R9: revert R8's counted-vmcnt/sched_barrier graft (m141 failure mode:
// order-pinning + compiler re-inserted waits -> 93us, VGPR 188, occ 11%).
// Back to R7 structure; new lever = OCCUPANCY. K4 was grid-capped at
// 2 blocks/CU x 4 waves = 8 waves/CU (19%). K4 now uses 512-thread blocks
// (8 waves): 2 blocks/CU x 8 waves = 16 waves/CU -> 2x latency hiding for
// the per-ks barrier drains. Per-wave: 16-pixel S-strip (acc_s[4][1]),
// 32kx32d agg tile (acc_a[2][2]) -> fewer VGPRs; __launch_bounds__(512,4)
// pins 4 waves/SIMD. LDS 76.8 -> 56 KB (xglds swizzled [128][128], wlds
// aliases dead As2+Bs2). wsum pre-reduced via 2KB LDS scratch.
// ---------------------------------------------------------------------------

#define N_  32
#define C_  512
#define P_  1024
#define E_  1024
#define G_  8
#define D_  128
#define K_  64

typedef __attribute__((ext_vector_type(8))) short bf16x8;
typedef __attribute__((ext_vector_type(4))) float f32x4;

__device__ __forceinline__ unsigned short f2b(float f) {
    union { float f; unsigned u; } v; v.f = f;
    unsigned r = (v.u + 0x7FFFu + ((v.u >> 16) & 1u)) >> 16;
    return (unsigned short)r;
}
__device__ __forceinline__ float b2f(unsigned short h) {
    union { unsigned u; float f; } v; v.u = ((unsigned)h) << 16;
    return v.f;
}

// async global->LDS 16B copy: LDS dest must be wave-uniform base + lane*16
__device__ __forceinline__ void gl_lds16(const void* g, void* l) {
    __builtin_amdgcn_global_load_lds(
        (const __attribute__((address_space(1))) void*)g,
        (__attribute__((address_space(3))) void*)l, 16, 0, 0);
}

// ---------------------------------------------------------------------------
// K0: convert W1 -> bf16 AND build V[g][k][c] = sum_d Wc[k][d]*W1[g*128+d][c]
__global__ __launch_bounds__(256) void k0_prep(const float* __restrict__ W1,
                                               const float* __restrict__ Wc,
                                               unsigned short* __restrict__ W1b,
                                               unsigned short* __restrict__ Vb) {
    int bid = blockIdx.x;
    int t = threadIdx.x;
    int i0 = bid * 512 + t;
    W1b[i0]       = f2b(W1[i0]);
    W1b[i0 + 256] = f2b(W1[i0 + 256]);
    int ch = bid & 1, k = (bid >> 1) & 63, g = bid >> 7;
    int c = ch * 256 + t;
    float acc = 0.f;
    #pragma unroll 8
    for (int d = 0; d < 128; ++d)
        acc += Wc[k * 128 + d] * W1[(g * 128 + d) * C_ + c];
    Vb[(g * 64 + k) * C_ + c] = f2b(acc);
}

// ---------------------------------------------------------------------------
// K1: per-pixel L2 norm over C, write x_hat transposed: xhat_t [N][P][C] bf16
__global__ __launch_bounds__(256) void k1_norm_transpose(const float* __restrict__ x,
                                                         unsigned short* __restrict__ xhat_t) {
    __shared__ short xc[128 * 256];   // [i][t]: c = (t>>6)*128+i, p = p0+(t&63)
    __shared__ float red[256];
    __shared__ float rn[64];
    int n = blockIdx.y;
    int p0 = blockIdx.x * 64;
    int t = threadIdx.x;
    int ps = t & 63, cs = t >> 6;

    float ss = 0.f;
    for (int i = 0; i < 128; ++i) {
        float v = x[((size_t)(n * C_ + cs * 128 + i)) * P_ + p0 + ps];
        ss += v * v;
        xc[i * 256 + t] = (short)f2b(v);     // lanes consecutive -> conflict-free
    }
    red[t] = ss;
    __syncthreads();
    if (t < 64) {
        float s = red[t] + red[64 + t] + red[128 + t] + red[192 + t];
        rn[t] = 1.0f / fmaxf(sqrtf(s), 1e-12f);
    }
    __syncthreads();

    float r = rn[ps];
    size_t base = ((size_t)(n * P_ + p0 + ps)) * C_ + cs * 128;
    #pragma unroll
    for (int jj = 0; jj < 16; ++jj) {
        bf16x8 o;
        #pragma unroll
        for (int j = 0; j < 8; ++j)
            o[j] = (short)f2b(b2f((unsigned short)xc[(jj * 8 + j) * 256 + t]) * r);
        *(bf16x8*)&xhat_t[base + jj * 8] = o;
    }
}

// ---------------------------------------------------------------------------
// K2: xe[n][e][p] = sum_c W1b[e][c] * xhat_t[n][p][c]   (bf16 MFMA GEMM, NT)
// grid (64, 32). BK=64, XOR-swizzled LDS columns (chunk ^= row&7).
__global__ __launch_bounds__(256) void k2_gemm_xe(const unsigned short* __restrict__ W1b,
                                                  const unsigned short* __restrict__ xhat_t,
                                                  unsigned short* __restrict__ xe) {
    __shared__ __align__(16) short As[128 * 64];
    __shared__ __align__(16) short Bs[128 * 64];
    int n = blockIdx.y;
    int e0 = (blockIdx.x >> 3) * 128;
    int p0 = (blockIdx.x & 7) * 128;
    int t = threadIdx.x;
    int w = t >> 6, l = t & 63, q = l >> 4, l15 = l & 15;
    int wr = w >> 1, wc = w & 1;

    f32x4 acc[4][4];
    #pragma unroll
    for (int mi = 0; mi < 4; ++mi)
        #pragma unroll
        for (int ni = 0; ni < 4; ++ni)
            acc[mi][ni] = (f32x4){0.f, 0.f, 0.f, 0.f};

    for (int ks = 0; ks < 8; ++ks) {
        int k0 = ks * 64;
        #pragma unroll
        for (int i = 0; i < 4; ++i) {
            int ch = i * 256 + t;
            int row = ch >> 3, c8 = ch & 7;
            gl_lds16(&W1b[(e0 + row) * C_ + k0 + ((c8 ^ (row & 7)) * 8)], &As[ch * 8]);
        }
        #pragma unroll
        for (int i = 0; i < 4; ++i) {
            int ch = i * 256 + t;
            int row = ch >> 3, c8 = ch & 7;
            gl_lds16(&xhat_t[((size_t)(n * P_ + p0 + row)) * C_ + k0 + ((c8 ^ (row & 7)) * 8)], &Bs[ch * 8]);
        }
        __syncthreads();

        #pragma unroll
        for (int kk = 0; kk < 2; ++kk) {
            bf16x8 af[4], bf[4];
            #pragma unroll
            for (int mi = 0; mi < 4; ++mi)
                af[mi] = *(const bf16x8*)&As[(wr * 64 + mi * 16 + l15) * 64 + (((kk * 4 + q) ^ (l15 & 7)) * 8)];
            #pragma unroll
            for (int ni = 0; ni < 4; ++ni)
                bf[ni] = *(const bf16x8*)&Bs[(wc * 64 + ni * 16 + l15) * 64 + (((kk * 4 + q) ^ (l15 & 7)) * 8)];
            #pragma unroll
            for (int mi = 0; mi < 4; ++mi)
                #pragma unroll
                for (int ni = 0; ni < 4; ++ni)
                    acc[mi][ni] = __builtin_amdgcn_mfma_f32_16x16x32_bf16(af[mi], bf[ni], acc[mi][ni], 0, 0, 0);
        }
        __syncthreads();
    }

    #pragma unroll
    for (int mi = 0; mi < 4; ++mi) {
        #pragma unroll
        for (int ni = 0; ni < 4; ++ni) {
            #pragma unroll
            for (int r = 0; r < 4; ++r) {
                int e = e0 + wr * 64 + mi * 16 + q * 4 + r;
                int p = p0 + wc * 64 + ni * 16 + l15;
                xe[((size_t)(n * E_ + e)) * P_ + p] = f2b(acc[mi][ni][r]);
            }
        }
    }
}

// ---------------------------------------------------------------------------
// K3a: att partials over 64-wide e-chunks, 4 pixels/thread (ushort4/float4).
__global__ __launch_bounds__(256) void k3a_att_part(const unsigned short* __restrict__ xe,
                                                    const float* __restrict__ W2,
                                                    float* __restrict__ att_part) {
    int n = blockIdx.y;
    int ec = blockIdx.x;
    int t = threadIdx.x;
    int e0 = ec * 64;
    f32x4 acc[8];
    #pragma unroll
    for (int g = 0; g < 8; ++g) acc[g] = (f32x4){0.f, 0.f, 0.f, 0.f};
    #pragma unroll 4
    for (int i = 0; i < 64; ++i) {
        int e = e0 + i;
        ushort4 v4 = *(const ushort4*)&xe[((size_t)(n * E_ + e)) * P_ + t * 4];
        f32x4 vf = {b2f(v4.x), b2f(v4.y), b2f(v4.z), b2f(v4.w)};
        #pragma unroll
        for (int g = 0; g < 8; ++g)
            acc[g] += vf * W2[g * E_ + e];
    }
    #pragma unroll
    for (int g = 0; g < 8; ++g)
        *(f32x4*)&att_part[(((size_t)(n * 16 + ec)) * 8 + g) * P_ + t * 4] = acc[g];
}

// K3b: att_s[n][g][p] = sigmoid( sum_ec att_part[n][ec][g][p] )
__global__ __launch_bounds__(256) void k3b_att_reduce(const float* __restrict__ att_part,
                                                      float* __restrict__ att_s) {
    int idx = blockIdx.x * 256 + threadIdx.x;
    int p = idx & 1023;
    int g = (idx >> 10) & 7;
    int n = idx >> 13;
    float s = 0.f;
    #pragma unroll
    for (int ec = 0; ec < 16; ++ec)
        s += att_part[(((size_t)(n * 16 + ec)) * 8 + g) * P_ + p];
    att_s[idx] = 1.0f / (1.0f + __expf(-s));
}

// ---------------------------------------------------------------------------
// K4: fused assignment -> softmax -> gate -> aggregation per (n, g, ph)
// grid (16, 32) x 512 threads (8 waves). 2 blocks/CU x 8 waves = 16 waves/CU.
// S phase: wave w owns pixels [w*16, w*16+16) of the 128-p cc tile.
// Agg phase: wave w owns (kh=w>>2)*32 k-rows x (dq=w&3)*32 d-cols.
// LDS 56 KB: As2 8K | Bs2 16K | xglds 32K; wlds aliases As2+Bs2 (dead).
__global__ __launch_bounds__(512, 4) void k4_assign_agg(const unsigned short* __restrict__ Vb,
                                                        const unsigned short* __restrict__ xhat_t,
                                                        const unsigned short* __restrict__ xe,
                                                        const float* __restrict__ att_s,
                                                        float* __restrict__ agg_part,
                                                        float* __restrict__ wsum_part) {
    __shared__ __align__(16) char smem[8192 + 16384 + 32768];
    short* As2   = (short*)smem;                    // [64][64]    8 KB (swizzled)
    short* Bs2   = (short*)(smem + 8192);           // [128][64]  16 KB (swizzled)
    short* xglds = (short*)(smem + 24576);          // [128][128] 32 KB (swizzled)
    short* wlds  = (short*)smem;                    // [64][136] 17.4 KB alias (As2+Bs2 dead)
    float* wred  = (float*)smem;                    // [8][64] 2 KB epilogue alias

    // XCD-aware remap (bijective: 512 blocks, 512 % 8 == 0)
    int b = blockIdx.y * 16 + blockIdx.x;
    int work = (b & 7) * 64 + (b >> 3);
    int n = work >> 4, g = work & 7, ph = (work >> 3) & 1;

    int t = threadIdx.x;
    int w = t >> 6, l = t & 63, q = l >> 4, l15 = l & 15;
    int kh = w >> 2, dq = w & 3;

    f32x4 acc_a[2][2];
    #pragma unroll
    for (int mi = 0; mi < 2; ++mi)
        #pragma unroll
        for (int ni = 0; ni < 2; ++ni)
            acc_a[mi][ni] = (f32x4){0.f, 0.f, 0.f, 0.f};
    float wsp[16];
    #pragma unroll
    for (int j = 0; j < 16; ++j) wsp[j] = 0.f;

    for (int cc = 0; cc < 4; ++cc) {
        int p0c = ph * 512 + cc * 128;

        // ---- issue xg staging FIRST (agg input; drains behind S barriers) ----
        // xglds [128][128] swizzled: 2048 chunks, 4/thread
        #pragma unroll
        for (int i = 0; i < 4; ++i) {
            int ch = i * 512 + t;
            int row = ch >> 4, c16 = ch & 15;
            gl_lds16(&xe[((size_t)(n * E_ + g * 128 + row)) * P_ + p0c + ((c16 ^ (row & 7)) * 8)],
                     &xglds[ch * 8]);
        }

        // ---- Phase S: S = Vb[g] (64xC) * xhat^T (Cx128), BK=64 ----
        f32x4 acc_s[4];
        #pragma unroll
        for (int mi = 0; mi < 4; ++mi)
            acc_s[mi] = (f32x4){0.f, 0.f, 0.f, 0.f};

        for (int ks = 0; ks < 8; ++ks) {
            int k0 = ks * 64;
            // As2: 512 chunks, 1/thread (source pre-swizzled)
            {
                int row = t >> 3, c8 = t & 7;
                gl_lds16(&Vb[(g * 64 + row) * C_ + k0 + ((c8 ^ (row & 7)) * 8)], &As2[t * 8]);
            }
            // Bs2: 1024 chunks, 2/thread (source pre-swizzled)
            #pragma unroll
            for (int i = 0; i < 2; ++i) {
                int ch = i * 512 + t;
                int row = ch >> 3, c8 = ch & 7;
                gl_lds16(&xhat_t[((size_t)(n * P_ + p0c + row)) * C_ + k0 + ((c8 ^ (row & 7)) * 8)], &Bs2[ch * 8]);
            }
            __syncthreads();
            #pragma unroll
            for (int kk = 0; kk < 2; ++kk) {
                bf16x8 af[4], bfr;
                #pragma unroll
                for (int mi = 0; mi < 4; ++mi)
                    af[mi] = *(const bf16x8*)&As2[(mi * 16 + l15) * 64 + (((kk * 4 + q) ^ (l15 & 7)) * 8)];
                bfr = *(const bf16x8*)&Bs2[(w * 16 + l15) * 64 + (((kk * 4 + q) ^ (l15 & 7)) * 8)];
                #pragma unroll
                for (int mi = 0; mi < 4; ++mi)
                    acc_s[mi] = __builtin_amdgcn_mfma_f32_16x16x32_bf16(af[mi], bfr, acc_s[mi], 0, 0, 0);
            }
            __syncthreads();
        }

        // ---- softmax over k + gate (wave strip = 16 pixels) ----
        {
            float m = -1e30f;
            #pragma unroll
            for (int mi = 0; mi < 4; ++mi)
                #pragma unroll
                for (int r = 0; r < 4; ++r)
                    m = fmaxf(m, acc_s[mi][r]);
            m = fmaxf(m, __shfl_xor(m, 16));
            m = fmaxf(m, __shfl_xor(m, 32));
            float s = 0.f;
            #pragma unroll
            for (int mi = 0; mi < 4; ++mi)
                #pragma unroll
                for (int r = 0; r < 4; ++r) {
                    float e = __expf(acc_s[mi][r] - m);
                    acc_s[mi][r] = e;
                    s += e;
                }
            s += __shfl_xor(s, 16);
            s += __shfl_xor(s, 32);

            float av = att_s[(((size_t)(n * G_ + g)) * P_) + p0c + w * 16 + l15];  // pre-sigmoided
            float scale = av / s;

            #pragma unroll
            for (int mi = 0; mi < 4; ++mi)
                #pragma unroll
                for (int r = 0; r < 4; ++r) {
                    float wv = acc_s[mi][r] * scale;
                    wsp[mi * 4 + r] += wv;
                    wlds[(mi * 16 + q * 4 + r) * 136 + (w * 16 + l15)] = (short)f2b(wv);
                }
        }
        __syncthreads();   // wlds visible; xglds DMA drained (vmcnt in syncthreads)

        // ---- agg MFMA: A = w [64k x 128p], B = xg [128d x 128p] (NT) ----
        // wave (kh,dq): 32 k-rows x 32 d-cols, full 128-p reduction
        #pragma unroll
        for (int pk = 0; pk < 4; ++pk) {
            bf16x8 a2[2], b2[2];
            #pragma unroll
            for (int mi = 0; mi < 2; ++mi)
                a2[mi] = *(const bf16x8*)&wlds[(kh * 32 + mi * 16 + l15) * 136 + pk * 32 + q * 8];
            #pragma unroll
            for (int ni = 0; ni < 2; ++ni)
                b2[ni] = *(const bf16x8*)&xglds[(dq * 32 + ni * 16 + l15) * 128
                                                + (((pk * 4 + q) ^ (l15 & 7)) * 8)];
            #pragma unroll
            for (int mi = 0; mi < 2; ++mi)
                #pragma unroll
                for (int ni = 0; ni < 2; ++ni)
                    acc_a[mi][ni] = __builtin_amdgcn_mfma_f32_16x16x32_bf16(a2[mi], b2[ni], acc_a[mi][ni], 0, 0, 0);
        }
        __syncthreads();   // xglds/wlds reads done before next cc re-stages
    }

    // ---- epilogue: disjoint partials, no atomics ----
    size_t base = (((size_t)(n * G_ + g)) * 2 + ph) * 64;
    #pragma unroll
    for (int mi = 0; mi < 2; ++mi)
        #pragma unroll
        for (int ni = 0; ni < 2; ++ni)
            #pragma unroll
            for (int r = 0; r < 4; ++r) {
                int k = kh * 32 + mi * 16 + q * 4 + r;
                int d = dq * 32 + ni * 16 + l15;
                agg_part[(base + k) * 128 + d] = acc_a[mi][ni][r];
            }

    // wsum: per-wave k-sums -> LDS -> one [64] vector per block
    #pragma unroll
    for (int j = 0; j < 16; ++j) {
        float v = wsp[j];
        v += __shfl_xor(v, 1);
        v += __shfl_xor(v, 2);
        v += __shfl_xor(v, 4);
        v += __shfl_xor(v, 8);
        if (l15 == 0) {
            int k = (j >> 2) * 16 + q * 4 + (j & 3);
            wred[w * 64 + k] = v;
        }
    }
    __syncthreads();
    if (t < 64) {
        float s = 0.f;
        #pragma unroll
        for (int wv = 0; wv < 8; ++wv)
            s += wred[wv * 64 + t];
        wsum_part[(((size_t)(n * G_ + g)) * 2 + ph) * 64 + t] = s;
    }
}

// ---------------------------------------------------------------------------
// K5: vlad[n][k][d] = sum_{g,ph} agg_part - (sum) * centroids
__global__ __launch_bounds__(256) void k5_final(const float* __restrict__ agg_part,
                                                const float* __restrict__ wsum_part,
                                                const float* __restrict__ centroids,
                                                float* __restrict__ out) {
    int idx = blockIdx.x * 256 + threadIdx.x;
    int d = idx & 127;
    int k = (idx >> 7) & 63;
    int n = idx >> 13;
    float ws = 0.f;
    #pragma unroll
    for (int g = 0; g < 8; ++g)
        #pragma unroll
        for (int ph = 0; ph < 2; ++ph)
            ws += wsum_part[(((size_t)(n * G_ + g)) * 2 + ph) * 64 + k];
    float agg = 0.f;
    #pragma unroll
    for (int g = 0; g < 8; ++g)
        #pragma unroll
        for (int ph = 0; ph < 2; ++ph)
            agg += agg_part[(((((size_t)(n * G_ + g)) * 2 + ph) * 64) + k) * 128 + d];
    out[idx] = agg - ws * centroids[k * 128 + d];
}

// ---------------------------------------------------------------------------
extern "C" void kernel_launch(void* const* d_in, const int* in_sizes, int n_in,
                              void* d_out, int out_size, void* d_ws, size_t ws_size,
                              hipStream_t stream) {
    const float* x         = (const float*)d_in[0];
    const float* W1        = (const float*)d_in[1];
    const float* W2        = (const float*)d_in[2];
    const float* Wc        = (const float*)d_in[3];
    const float* centroids = (const float*)d_in[4];
    float* out = (float*)d_out;

    // Workspace layout (total 120,324,096 B == proven footprint):
    //   W1b      [E*C]        bf16   1,048,576 B @ 0
    //   Vb       [G*K*C]      bf16     524,288 B @ 1,048,576
    //   xhat_t   [N*P*C]      bf16  33,554,432 B @ 1,572,864
    //   xe       [N*E*P]      bf16  67,108,864 B @ 35,127,296
    //   att_s    [N*G*P]      f32    1,048,576 B @ 102,236,160
    //   att_part [N*16*G*P]   f32   16,777,216 B @ 103,284,736 (dead after k3b;
    //   agg_part [N*G*2*K*D]  f32   16,777,216 B @ 103,284,736  aliases att_part)
    //   wsum_part[N*G*2*K]    f32      131,072 B @ 120,061,952
    char* ws = (char*)d_ws;
    unsigned short* W1b      = (unsigned short*)(ws + 0);
    unsigned short* Vb       = (unsigned short*)(ws + 1048576);
    unsigned short* xhat_t   = (unsigned short*)(ws + 1572864);
    unsigned short* xe       = (unsigned short*)(ws + 35127296);
    float*          att_s    = (float*)(ws + 102236160);
    float*          att_part = (float*)(ws + 103284736);
    float*          agg_part = (float*)(ws + 103284736);   // alias: att_part dead before K4
    float*          wsum_part= (float*)(ws + 120061952);

    hipLaunchKernelGGL(k0_prep,        dim3(1024), dim3(256), 0, stream, W1, Wc, W1b, Vb);
    hipLaunchKernelGGL(k1_norm_transpose, dim3(16, 32), dim3(256), 0, stream, x, xhat_t);
    hipLaunchKernelGGL(k2_gemm_xe,     dim3(64, 32), dim3(256), 0, stream, W1b, xhat_t, xe);
    hipLaunchKernelGGL(k3a_att_part,   dim3(16, 32), dim3(256), 0, stream, xe, W2, att_part);
    hipLaunchKernelGGL(k3b_att_reduce, dim3(1024), dim3(256), 0, stream, att_part, att_s);
    hipLaunchKernelGGL(k4_assign_agg,  dim3(16, 32), dim3(512), 0, stream, Vb, xhat_t, xe,
                       att_s, agg_part, wsum_part);
    hipLaunchKernelGGL(k5_final,       dim3(1024), dim3(256), 0, stream,
                       agg_part, wsum_part, centroids, out);
}

// Round 4
// 230.705 us; speedup vs baseline: 1.2111x; 1.0113x over previous
//
#include <hip/hip_runtime.h>

// ---------------------------------------------------------------------------
// TransVLAD fused pipeline for MI355X (gfx950)
// Shapes: N=32, C=512, H=W=32 (P=1024), E=1024, G=8, D=128, K=64
// out: [N, K*D] fp32 (262144)
//
// R10: K4's per-round __syncthreads drained vmcnt(0) every time (incl. the
// xg HBM prefetch at cc-top -> round 0 serially ate the whole 32KB xe tile).
// m201 pattern, avoiding R8's mistakes (NO register global loads in the
// ladder, SBs only at round boundaries): S-tile (As 8K + Bs 16K) double-
// buffered, raw s_barrier + counted vmcnt(3) so the next tile's DMA stays
// in flight across barriers; xg issued at round 6 (vmcnt 7/4) so its HBM
// transfer overlaps rounds 6-7 + softmax. att_s preloaded at cc-top.
// LDS 56 -> 80 KB (still 2 blocks/CU x 8 waves).
// ---------------------------------------------------------------------------

#define N_  32
#define C_  512
#define P_  1024
#define E_  1024
#define G_  8
#define D_  128
#define K_  64

typedef __attribute__((ext_vector_type(8))) short bf16x8;
typedef __attribute__((ext_vector_type(4))) float f32x4;

__device__ __forceinline__ unsigned short f2b(float f) {
    union { float f; unsigned u; } v; v.f = f;
    unsigned r = (v.u + 0x7FFFu + ((v.u >> 16) & 1u)) >> 16;
    return (unsigned short)r;
}
__device__ __forceinline__ float b2f(unsigned short h) {
    union { unsigned u; float f; } v; v.u = ((unsigned)h) << 16;
    return v.f;
}

// async global->LDS 16B copy: LDS dest must be wave-uniform base + lane*16
__device__ __forceinline__ void gl_lds16(const void* g, void* l) {
    __builtin_amdgcn_global_load_lds(
        (const __attribute__((address_space(1))) void*)g,
        (__attribute__((address_space(3))) void*)l, 16, 0, 0);
}

#define SB  __builtin_amdgcn_sched_barrier(0)
#define BAR __builtin_amdgcn_s_barrier()

// ---------------------------------------------------------------------------
// K0: convert W1 -> bf16 AND build V[g][k][c] = sum_d Wc[k][d]*W1[g*128+d][c]
__global__ __launch_bounds__(256) void k0_prep(const float* __restrict__ W1,
                                               const float* __restrict__ Wc,
                                               unsigned short* __restrict__ W1b,
                                               unsigned short* __restrict__ Vb) {
    int bid = blockIdx.x;
    int t = threadIdx.x;
    int i0 = bid * 512 + t;
    W1b[i0]       = f2b(W1[i0]);
    W1b[i0 + 256] = f2b(W1[i0 + 256]);
    int ch = bid & 1, k = (bid >> 1) & 63, g = bid >> 7;
    int c = ch * 256 + t;
    float acc = 0.f;
    #pragma unroll 8
    for (int d = 0; d < 128; ++d)
        acc += Wc[k * 128 + d] * W1[(g * 128 + d) * C_ + c];
    Vb[(g * 64 + k) * C_ + c] = f2b(acc);
}

// ---------------------------------------------------------------------------
// K1: per-pixel L2 norm over C, write x_hat transposed: xhat_t [N][P][C] bf16
__global__ __launch_bounds__(256) void k1_norm_transpose(const float* __restrict__ x,
                                                         unsigned short* __restrict__ xhat_t) {
    __shared__ short xc[128 * 256];   // [i][t]: c = (t>>6)*128+i, p = p0+(t&63)
    __shared__ float red[256];
    __shared__ float rn[64];
    int n = blockIdx.y;
    int p0 = blockIdx.x * 64;
    int t = threadIdx.x;
    int ps = t & 63, cs = t >> 6;

    float ss = 0.f;
    for (int i = 0; i < 128; ++i) {
        float v = x[((size_t)(n * C_ + cs * 128 + i)) * P_ + p0 + ps];
        ss += v * v;
        xc[i * 256 + t] = (short)f2b(v);     // lanes consecutive -> conflict-free
    }
    red[t] = ss;
    __syncthreads();
    if (t < 64) {
        float s = red[t] + red[64 + t] + red[128 + t] + red[192 + t];
        rn[t] = 1.0f / fmaxf(sqrtf(s), 1e-12f);
    }
    __syncthreads();

    float r = rn[ps];
    size_t base = ((size_t)(n * P_ + p0 + ps)) * C_ + cs * 128;
    #pragma unroll
    for (int jj = 0; jj < 16; ++jj) {
        bf16x8 o;
        #pragma unroll
        for (int j = 0; j < 8; ++j)
            o[j] = (short)f2b(b2f((unsigned short)xc[(jj * 8 + j) * 256 + t]) * r);
        *(bf16x8*)&xhat_t[base + jj * 8] = o;
    }
}

// ---------------------------------------------------------------------------
// K2: xe[n][e][p] = sum_c W1b[e][c] * xhat_t[n][p][c]   (bf16 MFMA GEMM, NT)
// grid (64, 32). BK=64, XOR-swizzled LDS columns (chunk ^= row&7).
__global__ __launch_bounds__(256) void k2_gemm_xe(const unsigned short* __restrict__ W1b,
                                                  const unsigned short* __restrict__ xhat_t,
                                                  unsigned short* __restrict__ xe) {
    __shared__ __align__(16) short As[128 * 64];
    __shared__ __align__(16) short Bs[128 * 64];
    int n = blockIdx.y;
    int e0 = (blockIdx.x >> 3) * 128;
    int p0 = (blockIdx.x & 7) * 128;
    int t = threadIdx.x;
    int w = t >> 6, l = t & 63, q = l >> 4, l15 = l & 15;
    int wr = w >> 1, wc = w & 1;

    f32x4 acc[4][4];
    #pragma unroll
    for (int mi = 0; mi < 4; ++mi)
        #pragma unroll
        for (int ni = 0; ni < 4; ++ni)
            acc[mi][ni] = (f32x4){0.f, 0.f, 0.f, 0.f};

    for (int ks = 0; ks < 8; ++ks) {
        int k0 = ks * 64;
        #pragma unroll
        for (int i = 0; i < 4; ++i) {
            int ch = i * 256 + t;
            int row = ch >> 3, c8 = ch & 7;
            gl_lds16(&W1b[(e0 + row) * C_ + k0 + ((c8 ^ (row & 7)) * 8)], &As[ch * 8]);
        }
        #pragma unroll
        for (int i = 0; i < 4; ++i) {
            int ch = i * 256 + t;
            int row = ch >> 3, c8 = ch & 7;
            gl_lds16(&xhat_t[((size_t)(n * P_ + p0 + row)) * C_ + k0 + ((c8 ^ (row & 7)) * 8)], &Bs[ch * 8]);
        }
        __syncthreads();

        #pragma unroll
        for (int kk = 0; kk < 2; ++kk) {
            bf16x8 af[4], bf[4];
            #pragma unroll
            for (int mi = 0; mi < 4; ++mi)
                af[mi] = *(const bf16x8*)&As[(wr * 64 + mi * 16 + l15) * 64 + (((kk * 4 + q) ^ (l15 & 7)) * 8)];
            #pragma unroll
            for (int ni = 0; ni < 4; ++ni)
                bf[ni] = *(const bf16x8*)&Bs[(wc * 64 + ni * 16 + l15) * 64 + (((kk * 4 + q) ^ (l15 & 7)) * 8)];
            #pragma unroll
            for (int mi = 0; mi < 4; ++mi)
                #pragma unroll
                for (int ni = 0; ni < 4; ++ni)
                    acc[mi][ni] = __builtin_amdgcn_mfma_f32_16x16x32_bf16(af[mi], bf[ni], acc[mi][ni], 0, 0, 0);
        }
        __syncthreads();
    }

    #pragma unroll
    for (int mi = 0; mi < 4; ++mi) {
        #pragma unroll
        for (int ni = 0; ni < 4; ++ni) {
            #pragma unroll
            for (int r = 0; r < 4; ++r) {
                int e = e0 + wr * 64 + mi * 16 + q * 4 + r;
                int p = p0 + wc * 64 + ni * 16 + l15;
                xe[((size_t)(n * E_ + e)) * P_ + p] = f2b(acc[mi][ni][r]);
            }
        }
    }
}

// ---------------------------------------------------------------------------
// K3a: att partials over 64-wide e-chunks, 4 pixels/thread (ushort4/float4).
__global__ __launch_bounds__(256) void k3a_att_part(const unsigned short* __restrict__ xe,
                                                    const float* __restrict__ W2,
                                                    float* __restrict__ att_part) {
    int n = blockIdx.y;
    int ec = blockIdx.x;
    int t = threadIdx.x;
    int e0 = ec * 64;
    f32x4 acc[8];
    #pragma unroll
    for (int g = 0; g < 8; ++g) acc[g] = (f32x4){0.f, 0.f, 0.f, 0.f};
    #pragma unroll 4
    for (int i = 0; i < 64; ++i) {
        int e = e0 + i;
        ushort4 v4 = *(const ushort4*)&xe[((size_t)(n * E_ + e)) * P_ + t * 4];
        f32x4 vf = {b2f(v4.x), b2f(v4.y), b2f(v4.z), b2f(v4.w)};
        #pragma unroll
        for (int g = 0; g < 8; ++g)
            acc[g] += vf * W2[g * E_ + e];
    }
    #pragma unroll
    for (int g = 0; g < 8; ++g)
        *(f32x4*)&att_part[(((size_t)(n * 16 + ec)) * 8 + g) * P_ + t * 4] = acc[g];
}

// K3b: att_s[n][g][p] = sigmoid( sum_ec att_part[n][ec][g][p] )
__global__ __launch_bounds__(256) void k3b_att_reduce(const float* __restrict__ att_part,
                                                      float* __restrict__ att_s) {
    int idx = blockIdx.x * 256 + threadIdx.x;
    int p = idx & 1023;
    int g = (idx >> 10) & 7;
    int n = idx >> 13;
    float s = 0.f;
    #pragma unroll
    for (int ec = 0; ec < 16; ++ec)
        s += att_part[(((size_t)(n * 16 + ec)) * 8 + g) * P_ + p];
    att_s[idx] = 1.0f / (1.0f + __expf(-s));
}

// ---------------------------------------------------------------------------
// K4 helpers (512-thread variants)
// stage one 24 KB S-tile: As [64][64] @ sb, Bs [128][64] @ sb+4096 (shorts)
__device__ __forceinline__ void stage_s(short* sb, const unsigned short* __restrict__ Vb,
                                        const unsigned short* __restrict__ xhat_t,
                                        int g, int n, int p0c, int k0, int t) {
    {
        int row = t >> 3, c8 = t & 7;
        gl_lds16(&Vb[(g * 64 + row) * C_ + k0 + ((c8 ^ (row & 7)) * 8)], &sb[t * 8]);
    }
    #pragma unroll
    for (int i = 0; i < 2; ++i) {
        int ch = i * 512 + t;
        int row = ch >> 3, c8 = ch & 7;
        gl_lds16(&xhat_t[((size_t)(n * P_ + p0c + row)) * C_ + k0 + ((c8 ^ (row & 7)) * 8)],
                 &sb[4096 + ch * 8]);
    }
}

__device__ __forceinline__ void stage_xg(short* xglds, const unsigned short* __restrict__ xe,
                                         int n, int g, int p0c, int t) {
    #pragma unroll
    for (int i = 0; i < 4; ++i) {
        int ch = i * 512 + t;
        int row = ch >> 4, c16 = ch & 15;
        gl_lds16(&xe[((size_t)(n * E_ + g * 128 + row)) * P_ + p0c + ((c16 ^ (row & 7)) * 8)],
                 &xglds[ch * 8]);
    }
}

__device__ __forceinline__ void mfma_s(f32x4 acc[4], const short* sb, int w, int q, int l15) {
    #pragma unroll
    for (int kk = 0; kk < 2; ++kk) {
        bf16x8 af[4], bfr;
        #pragma unroll
        for (int mi = 0; mi < 4; ++mi)
            af[mi] = *(const bf16x8*)&sb[(mi * 16 + l15) * 64 + (((kk * 4 + q) ^ (l15 & 7)) * 8)];
        bfr = *(const bf16x8*)&sb[4096 + (w * 16 + l15) * 64 + (((kk * 4 + q) ^ (l15 & 7)) * 8)];
        #pragma unroll
        for (int mi = 0; mi < 4; ++mi)
            acc[mi] = __builtin_amdgcn_mfma_f32_16x16x32_bf16(af[mi], bfr, acc[mi], 0, 0, 0);
    }
}

// ---------------------------------------------------------------------------
// K4: fused assignment -> softmax -> gate -> aggregation per (n, g, ph)
// grid (16, 32) x 512 threads. Double-buffered S-tile, counted-vmcnt rounds.
__global__ __launch_bounds__(512, 4) void k4_assign_agg(const unsigned short* __restrict__ Vb,
                                                        const unsigned short* __restrict__ xhat_t,
                                                        const unsigned short* __restrict__ xe,
                                                        const float* __restrict__ att_s,
                                                        float* __restrict__ agg_part,
                                                        float* __restrict__ wsum_part) {
    __shared__ __align__(16) char smem[81920];
    short* S0    = (short*)smem;                 // 24 KB: As 8K + Bs 16K
    short* S1    = (short*)(smem + 24576);       // 24 KB
    short* xglds = (short*)(smem + 49152);       // [128][128] 32 KB (swizzled)
    short* wlds  = (short*)smem;                 // [64][136] 17.4 KB alias over S0
    float* wred  = (float*)smem;                 // [8][64] 2 KB epilogue alias

    // XCD-aware remap (bijective: 512 blocks, 512 % 8 == 0)
    int b = blockIdx.y * 16 + blockIdx.x;
    int work = (b & 7) * 64 + (b >> 3);
    int n = work >> 4, g = work & 7, ph = (work >> 3) & 1;

    int t = threadIdx.x;
    int w = t >> 6, l = t & 63, q = l >> 4, l15 = l & 15;
    int kh = w >> 2, dq = w & 3;

    f32x4 acc_a[2][2];
    #pragma unroll
    for (int mi = 0; mi < 2; ++mi)
        #pragma unroll
        for (int ni = 0; ni < 2; ++ni)
            acc_a[mi][ni] = (f32x4){0.f, 0.f, 0.f, 0.f};
    float wsp[16];
    #pragma unroll
    for (int j = 0; j < 16; ++j) wsp[j] = 0.f;

#define WAITV(n_) asm volatile("s_waitcnt vmcnt(" #n_ ")" ::: "memory")
#define RND(CUR, NXT, KN) \
    stage_s(NXT, Vb, xhat_t, g, n, p0c, (KN) * 64, t); \
    WAITV(3); BAR; SB; \
    mfma_s(acc_s, CUR, w, q, l15); \
    BAR; SB;

    #pragma unroll 1
    for (int cc = 0; cc < 4; ++cc) {
        int p0c = ph * 512 + cc * 128;

        // att gate value for this wave's 16-pixel strip (oldest VMEM op;
        // drained by round-0's vmcnt(3), consumed in softmax)
        float av = att_s[(((size_t)(n * G_ + g)) * P_) + p0c + w * 16 + l15];

        f32x4 acc_s[4];
        #pragma unroll
        for (int mi = 0; mi < 4; ++mi)
            acc_s[mi] = (f32x4){0.f, 0.f, 0.f, 0.f};

        // ---- Phase S: S = Vb[g] (64xC) * xhat^T (Cx128), BK=64, dbuf ----
        stage_s(S0, Vb, xhat_t, g, n, p0c, 0, t);       // prologue: ks=0
        RND(S0, S1, 1)                                  // reads ks0, stages ks1
        RND(S1, S0, 2)
        RND(S0, S1, 3)
        RND(S1, S0, 4)
        RND(S0, S1, 5)
        RND(S1, S0, 6)
        // round reading ks=6: stage ks=7 AND xg (HBM) -> both stay in flight
        stage_s(S1, Vb, xhat_t, g, n, p0c, 448, t);
        stage_xg(xglds, xe, n, g, p0c, t);
        WAITV(7); BAR; SB;
        mfma_s(acc_s, S0, w, q, l15);
        BAR; SB;
        // round reading ks=7: xg (4 ops) still outstanding
        WAITV(4); BAR; SB;
        mfma_s(acc_s, S1, w, q, l15);
        BAR; SB;

        // ---- softmax over k + gate (wave strip = 16 pixels) ----
        {
            float m = -1e30f;
            #pragma unroll
            for (int mi = 0; mi < 4; ++mi)
                #pragma unroll
                for (int r = 0; r < 4; ++r)
                    m = fmaxf(m, acc_s[mi][r]);
            m = fmaxf(m, __shfl_xor(m, 16));
            m = fmaxf(m, __shfl_xor(m, 32));
            float s = 0.f;
            #pragma unroll
            for (int mi = 0; mi < 4; ++mi)
                #pragma unroll
                for (int r = 0; r < 4; ++r) {
                    float e = __expf(acc_s[mi][r] - m);
                    acc_s[mi][r] = e;
                    s += e;
                }
            s += __shfl_xor(s, 16);
            s += __shfl_xor(s, 32);

            float scale = av / s;   // av pre-sigmoided

            #pragma unroll
            for (int mi = 0; mi < 4; ++mi)
                #pragma unroll
                for (int r = 0; r < 4; ++r) {
                    float wv = acc_s[mi][r] * scale;
                    wsp[mi * 4 + r] += wv;
                    wlds[(mi * 16 + q * 4 + r) * 136 + (w * 16 + l15)] = (short)f2b(wv);
                }
        }
        __syncthreads();   // drains xg DMA (vmcnt) + wlds writes (lgkmcnt)

        // ---- agg MFMA: A = w [64k x 128p], B = xg [128d x 128p] (NT) ----
        // wave (kh,dq): 32 k-rows x 32 d-cols, full 128-p reduction
        #pragma unroll
        for (int pk = 0; pk < 4; ++pk) {
            bf16x8 a2[2], b2[2];
            #pragma unroll
            for (int mi = 0; mi < 2; ++mi)
                a2[mi] = *(const bf16x8*)&wlds[(kh * 32 + mi * 16 + l15) * 136 + pk * 32 + q * 8];
            #pragma unroll
            for (int ni = 0; ni < 2; ++ni)
                b2[ni] = *(const bf16x8*)&xglds[(dq * 32 + ni * 16 + l15) * 128
                                                + (((pk * 4 + q) ^ (l15 & 7)) * 8)];
            #pragma unroll
            for (int mi = 0; mi < 2; ++mi)
                #pragma unroll
                for (int ni = 0; ni < 2; ++ni)
                    acc_a[mi][ni] = __builtin_amdgcn_mfma_f32_16x16x32_bf16(a2[mi], b2[ni], acc_a[mi][ni], 0, 0, 0);
        }
        __syncthreads();   // xglds/wlds reads done before next cc re-stages
    }

    // ---- epilogue: disjoint partials, no atomics ----
    size_t base = (((size_t)(n * G_ + g)) * 2 + ph) * 64;
    #pragma unroll
    for (int mi = 0; mi < 2; ++mi)
        #pragma unroll
        for (int ni = 0; ni < 2; ++ni)
            #pragma unroll
            for (int r = 0; r < 4; ++r) {
                int k = kh * 32 + mi * 16 + q * 4 + r;
                int d = dq * 32 + ni * 16 + l15;
                agg_part[(base + k) * 128 + d] = acc_a[mi][ni][r];
            }

    // wsum: per-wave k-sums -> LDS -> one [64] vector per block
    #pragma unroll
    for (int j = 0; j < 16; ++j) {
        float v = wsp[j];
        v += __shfl_xor(v, 1);
        v += __shfl_xor(v, 2);
        v += __shfl_xor(v, 4);
        v += __shfl_xor(v, 8);
        if (l15 == 0) {
            int k = (j >> 2) * 16 + q * 4 + (j & 3);
            wred[w * 64 + k] = v;
        }
    }
    __syncthreads();
    if (t < 64) {
        float s = 0.f;
        #pragma unroll
        for (int wv = 0; wv < 8; ++wv)
            s += wred[wv * 64 + t];
        wsum_part[(((size_t)(n * G_ + g)) * 2 + ph) * 64 + t] = s;
    }
}

// ---------------------------------------------------------------------------
// K5: vlad[n][k][d] = sum_{g,ph} agg_part - (sum) * centroids
__global__ __launch_bounds__(256) void k5_final(const float* __restrict__ agg_part,
                                                const float* __restrict__ wsum_part,
                                                const float* __restrict__ centroids,
                                                float* __restrict__ out) {
    int idx = blockIdx.x * 256 + threadIdx.x;
    int d = idx & 127;
    int k = (idx >> 7) & 63;
    int n = idx >> 13;
    float ws = 0.f;
    #pragma unroll
    for (int g = 0; g < 8; ++g)
        #pragma unroll
        for (int ph = 0; ph < 2; ++ph)
            ws += wsum_part[(((size_t)(n * G_ + g)) * 2 + ph) * 64 + k];
    float agg = 0.f;
    #pragma unroll
    for (int g = 0; g < 8; ++g)
        #pragma unroll
        for (int ph = 0; ph < 2; ++ph)
            agg += agg_part[(((((size_t)(n * G_ + g)) * 2 + ph) * 64) + k) * 128 + d];
    out[idx] = agg - ws * centroids[k * 128 + d];
}

// ---------------------------------------------------------------------------
extern "C" void kernel_launch(void* const* d_in, const int* in_sizes, int n_in,
                              void* d_out, int out_size, void* d_ws, size_t ws_size,
                              hipStream_t stream) {
    const float* x         = (const float*)d_in[0];
    const float* W1        = (const float*)d_in[1];
    const float* W2        = (const float*)d_in[2];
    const float* Wc        = (const float*)d_in[3];
    const float* centroids = (const float*)d_in[4];
    float* out = (float*)d_out;

    // Workspace layout (total 120,324,096 B == proven footprint):
    //   W1b      [E*C]        bf16   1,048,576 B @ 0
    //   Vb       [G*K*C]      bf16     524,288 B @ 1,048,576
    //   xhat_t   [N*P*C]      bf16  33,554,432 B @ 1,572,864
    //   xe       [N*E*P]      bf16  67,108,864 B @ 35,127,296
    //   att_s    [N*G*P]      f32    1,048,576 B @ 102,236,160
    //   att_part [N*16*G*P]   f32   16,777,216 B @ 103,284,736 (dead after k3b;
    //   agg_part [N*G*2*K*D]  f32   16,777,216 B @ 103,284,736  aliases att_part)
    //   wsum_part[N*G*2*K]    f32      131,072 B @ 120,061,952
    char* ws = (char*)d_ws;
    unsigned short* W1b      = (unsigned short*)(ws + 0);
    unsigned short* Vb       = (unsigned short*)(ws + 1048576);
    unsigned short* xhat_t   = (unsigned short*)(ws + 1572864);
    unsigned short* xe       = (unsigned short*)(ws + 35127296);
    float*          att_s    = (float*)(ws + 102236160);
    float*          att_part = (float*)(ws + 103284736);
    float*          agg_part = (float*)(ws + 103284736);   // alias: att_part dead before K4
    float*          wsum_part= (float*)(ws + 120061952);

    hipLaunchKernelGGL(k0_prep,        dim3(1024), dim3(256), 0, stream, W1, Wc, W1b, Vb);
    hipLaunchKernelGGL(k1_norm_transpose, dim3(16, 32), dim3(256), 0, stream, x, xhat_t);
    hipLaunchKernelGGL(k2_gemm_xe,     dim3(64, 32), dim3(256), 0, stream, W1b, xhat_t, xe);
    hipLaunchKernelGGL(k3a_att_part,   dim3(16, 32), dim3(256), 0, stream, xe, W2, att_part);
    hipLaunchKernelGGL(k3b_att_reduce, dim3(1024), dim3(256), 0, stream, att_part, att_s);
    hipLaunchKernelGGL(k4_assign_agg,  dim3(16, 32), dim3(512), 0, stream, Vb, xhat_t, xe,
                       att_s, agg_part, wsum_part);
    hipLaunchKernelGGL(k5_final,       dim3(1024), dim3(256), 0, stream,
                       agg_part, wsum_part, centroids, out);
}